// Round 8
// baseline (101.062 us; speedup 1.0000x reference)
//
#include <hip/hip_runtime.h>

#define ND 512   // directions
#define NP 64    // points per ray
#define NR 32    // rank
#define NF 256   // virtual subcarriers

#define PLANE (ND * NP * NR)        // 1,048,576 ushorts (2 MB) per cum plane
#define B0 (2 * PLANE)              // vr plane (NF*NR ushorts)
#define B1 (2 * PLANE + NF * NR)    // vi plane
// ws usage: (2*PLANE + 2*NF*NR)*2 B ~= 4.2 MB

typedef __attribute__((ext_vector_type(8))) short bf16x8;   // 8 bf16 = 4 VGPRs
typedef __attribute__((ext_vector_type(4))) float f32x4;
typedef __attribute__((ext_vector_type(4))) unsigned int uint4v;

// float -> bf16 (RNE); inputs are finite.
__device__ inline unsigned short f2bf(float x) {
    unsigned u = __builtin_bit_cast(unsigned, x);
    u += 0x7FFFu + ((u >> 16) & 1u);
    return (unsigned short)(u >> 16);
}
__device__ inline unsigned pack2(float a, float b) {
    return (unsigned)f2bf(a) | ((unsigned)f2bf(b) << 16);
}
__device__ inline bf16x8 cvt8(float4 a, float4 b) {
    uint4v u = {pack2(a.x, a.y), pack2(a.z, a.w), pack2(b.x, b.y), pack2(b.z, b.w)};
    return __builtin_bit_cast(bf16x8, u);
}
// negate 8 packed bf16 (sign-bit XOR)
__device__ inline bf16x8 neg8(bf16x8 v) {
    uint4v u = __builtin_bit_cast(uint4v, v);
    u ^= (uint4v){0x80008000u, 0x80008000u, 0x80008000u, 0x80008000u};
    return __builtin_bit_cast(bf16x8, u);
}

// ---- prep (barrier-free): cum planes + bf16 freq planes into ws ----
// Blocks 0..127: thread = (d, reim, r) chain; store dt*cum_re / -dt*cum_im,
// p=0 row zeroed (second-order p>=1 restriction becomes automatic).
// Blocks 128..129: freq_re / freq_im -> bf16.
__global__ __launch_bounds__(256) void lrrt_prep_kernel(
    const float* __restrict__ att_re, const float* __restrict__ att_im,
    const float* __restrict__ fre, const float* __restrict__ fim,
    const int* __restrict__ mrl, unsigned short* __restrict__ ws)
{
    const int t = threadIdx.x;
    const int bid = blockIdx.x;
    if (bid < 128) {
        const int tid = bid * 256 + t;        // 0..32767
        const int d = tid >> 6;
        const int reim = (tid >> 5) & 1;
        const int r = tid & 31;
        const float dt = (float)(*mrl) / (float)NP;
        const float sc = reim ? -dt : dt;
        const float* src = reim ? att_im : att_re;
        const size_t base = (size_t)d * (NP * NR);
        unsigned short* dst = ws + (size_t)reim * PLANE + base;
        float run = src[base + r];
        dst[r] = 0;                            // p = 0 excluded
#pragma unroll
        for (int p = 1; p < NP; ++p) {
            run += src[base + (size_t)p * NR + r];
            dst[(size_t)p * NR + r] = f2bf(sc * run);
        }
    } else {
        const int plane = bid - 128;          // 0 = vr, 1 = vi
        const float* src = plane ? fim : fre;
        unsigned short* dst = ws + B0 + plane * (NF * NR);
        for (int k = t; k < (NF * NR) / 4; k += 256) {
            const float4 x = *(const float4*)(src + (size_t)k * 4);
            *(uint2*)(dst + (size_t)k * 4) =
                make_uint2(pack2(x.x, x.y), pack2(x.z, x.w));
        }
    }
}

// ---- main: one block per (direction d, freq-half h); 4 independent waves ----
// Wave wv owns p-strip 16wv..16wv+15; A-frags load DIRECTLY from global
// ([p][r] natural layout == A-fragment layout, verified R6-k2), cum/B frags
// come pre-converted from ws. No barriers until the final block reduce.
// Chained-MFMA conj pattern (verified R3-R7):
//   re = mfma(x_i, vi, mfma(x_r, vr, 0)),  im = mfma(x_i, -vr, mfma(x_r, vi, 0))
__global__ __launch_bounds__(256, 4) void lrrt_main_kernel(
    const float* __restrict__ att_re, const float* __restrict__ att_im,
    const float* __restrict__ rad_re, const float* __restrict__ rad_im,
    const unsigned short* __restrict__ ws, const int* __restrict__ mrl,
    float* __restrict__ out)
{
    __shared__ float s_red[4][128][2];        // 4 KB

    const int t = threadIdx.x;
    const int h = blockIdx.x & 1;
    const int d = blockIdx.x >> 1;
    const int lane = t & 63, wv = t >> 6, kg = lane >> 4, m_lo = lane & 15;
    const int p = wv * 16 + m_lo;
    const size_t arow = (size_t)d * (NP * NR) + (size_t)p * NR + 8 * kg;

    // A fragments: global fp32 -> bf16 registers (coalesced float4 pairs)
    const bf16x8 a_r = cvt8(*(const float4*)(att_re + arow),
                            *(const float4*)(att_re + arow + 4));
    const bf16x8 a_i = cvt8(*(const float4*)(att_im + arow),
                            *(const float4*)(att_im + arow + 4));
    const bf16x8 r_r = cvt8(*(const float4*)(rad_re + arow),
                            *(const float4*)(rad_re + arow + 4));
    const bf16x8 r_i = cvt8(*(const float4*)(rad_im + arow),
                            *(const float4*)(rad_im + arow + 4));
    // cum fragments: ready-made bf16 (dt*cum_re, -dt*cum_im)
    const bf16x8 c_r = *(const bf16x8*)(ws + arow);
    const bf16x8 c_i = *(const bf16x8*)(ws + PLANE + arow);

    const float dt = (float)(*mrl) / (float)NP;
    const f32x4 zero = {0.f, 0.f, 0.f, 0.f};

#pragma unroll 1
    for (int q = 0; q < 8; ++q) {
        const int f = 16 * (8 * h + q) + m_lo;
        const size_t boff = (size_t)f * NR + 8 * kg;
        const bf16x8 vr = *(const bf16x8*)(ws + B0 + boff);
        const bf16x8 vi = *(const bf16x8*)(ws + B1 + boff);
        const bf16x8 vn = neg8(vr);

        f32x4 Are = __builtin_amdgcn_mfma_f32_16x16x32_bf16(a_r, vr, zero, 0, 0, 0);
        f32x4 Aim = __builtin_amdgcn_mfma_f32_16x16x32_bf16(a_r, vi, zero, 0, 0, 0);
        f32x4 Bre = __builtin_amdgcn_mfma_f32_16x16x32_bf16(r_r, vr, zero, 0, 0, 0);
        f32x4 Bim = __builtin_amdgcn_mfma_f32_16x16x32_bf16(r_r, vi, zero, 0, 0, 0);
        f32x4 Ure = __builtin_amdgcn_mfma_f32_16x16x32_bf16(c_r, vr, zero, 0, 0, 0);
        f32x4 Uim = __builtin_amdgcn_mfma_f32_16x16x32_bf16(c_r, vi, zero, 0, 0, 0);
        Are = __builtin_amdgcn_mfma_f32_16x16x32_bf16(a_i, vi, Are, 0, 0, 0);
        Aim = __builtin_amdgcn_mfma_f32_16x16x32_bf16(a_i, vn, Aim, 0, 0, 0);
        Bre = __builtin_amdgcn_mfma_f32_16x16x32_bf16(r_i, vi, Bre, 0, 0, 0);
        Bim = __builtin_amdgcn_mfma_f32_16x16x32_bf16(r_i, vn, Bim, 0, 0, 0);
        Ure = __builtin_amdgcn_mfma_f32_16x16x32_bf16(c_i, vi, Ure, 0, 0, 0);
        Uim = __builtin_amdgcn_mfma_f32_16x16x32_bf16(c_i, vn, Uim, 0, 0, 0);

        float sr = 0.f, si = 0.f;
#pragma unroll
        for (int i = 0; i < 4; ++i) {
            const float qre = Bre[i] * Are[i] - Bim[i] * Aim[i];
            const float qim = Bre[i] * Aim[i] + Bim[i] * Are[i];
            const float cre = 1.0f + Ure[i];   // dt folded into cum planes
            const float cim = Uim[i];
            sr = fmaf(qre, cre, fmaf(-qim, cim, sr));
            si = fmaf(qim, cre, fmaf(qre, cim, si));
        }
        // reduce over the 4 row-groups (p within the wave's strip)
        sr += __shfl_xor(sr, 16, 64); si += __shfl_xor(si, 16, 64);
        sr += __shfl_xor(sr, 32, 64); si += __shfl_xor(si, 32, 64);
        if (lane < 16) {
            s_red[wv][16 * q + lane][0] = sr;
            s_red[wv][16 * q + lane][1] = si;
        }
    }
    __syncthreads();   // the ONLY barrier

    // cross-wave sum; one atomic per (f, comp) per block (planar out)
    const float scale = dt / (float)ND;
    {
        const int lf = t >> 1, comp = t & 1;
        const float v = s_red[0][lf][comp] + s_red[1][lf][comp]
                      + s_red[2][lf][comp] + s_red[3][lf][comp];
        atomicAdd(&out[comp * NF + h * 128 + lf], v * scale);
    }
}

extern "C" void kernel_launch(void* const* d_in, const int* in_sizes, int n_in,
                              void* d_out, int out_size, void* d_ws, size_t ws_size,
                              hipStream_t stream) {
    const float* att_re = (const float*)d_in[0];
    const float* att_im = (const float*)d_in[1];
    const float* rad_re = (const float*)d_in[2];
    const float* rad_im = (const float*)d_in[3];
    const float* freq_re = (const float*)d_in[4];
    const float* freq_im = (const float*)d_in[5];
    const int* mrl = (const int*)d_in[6];
    float* out = (float*)d_out;
    unsigned short* ws = (unsigned short*)d_ws;

    // d_out is poisoned 0xAA before every launch; we accumulate with atomics.
    hipMemsetAsync(d_out, 0, (size_t)out_size * sizeof(float), stream);

    lrrt_prep_kernel<<<130, 256, 0, stream>>>(att_re, att_im, freq_re, freq_im, mrl, ws);
    lrrt_main_kernel<<<2 * ND, 256, 0, stream>>>(
        att_re, att_im, rad_re, rad_im, ws, mrl, out);
}